// Round 5
// baseline (294.816 us; speedup 1.0000x reference)
//
#include <hip/hip_runtime.h>
#include <hip/hip_bf16.h>

// ---------------------------------------------------------------------------
// Attention: B=2,N=2048,C=768,H=12,HD=64.  fp32 in/out, f16 MFMA internals.
//   K1: convert x, W_qkv, W_proj fp32 -> f16 in ws
//   K2: qk[token][1536] = x @ Wqkv^T[:1536] + b ; V^T -> vth[bh][64][2048]
//   K3: flash attention, S^T formulation: K/V frags straight from global,
//       per-wave P round-trip in LDS, no barriers, no transposes
//   K4: out = ao @ Wproj^T + b  -> float d_out
// ---------------------------------------------------------------------------

typedef _Float16 half8 __attribute__((ext_vector_type(8)));
typedef _Float16 half4_t __attribute__((ext_vector_type(4)));
typedef float floatx4 __attribute__((ext_vector_type(4)));

#define LDA 72                      // GEMM LDS row stride in halves (64+8 pad)
#define LDP 72                      // K3 P-matrix LDS row stride
#define SCALE_LOG2E 0.1803368801111204f   // (1/8) * log2(e)

// ws layout in _Float16 elements (total 14942208 halves = 29.9 MB)
constexpr int XH_OFF    = 0;                          // x as f16: 4096*768
constexpr int WQKV_OFF  = XH_OFF + 4096 * 768;        // 3145728
constexpr int WPROJ_OFF = WQKV_OFF + 2304 * 768;      // 4915200
constexpr int QK_OFF    = WPROJ_OFF + 768 * 768;      // 5505024   [token][1536]
constexpr int VTH_OFF   = QK_OFF + 4096 * 1536;       // 11796480  [bh][64][2048]

// ---------------------------------------------------------------- K1: convert
__global__ __launch_bounds__(256) void cvt_all(const float* __restrict__ x,
                                               const float* __restrict__ wqkv,
                                               const float* __restrict__ wproj,
                                               _Float16* __restrict__ ws) {
  constexpr int n1 = 4096 * 768 / 4;
  constexpr int n2 = 2304 * 768 / 4;
  int i = blockIdx.x * 256 + threadIdx.x;
  const float* src; _Float16* dst; int j;
  if (i < n1)           { src = x;     dst = ws + XH_OFF;    j = i; }
  else if (i < n1 + n2) { src = wqkv;  dst = ws + WQKV_OFF;  j = i - n1; }
  else                  { src = wproj; dst = ws + WPROJ_OFF; j = i - n1 - n2; }
  floatx4 f = *(const floatx4*)(src + 4 * j);
  half4_t h;
  h[0] = (_Float16)f[0]; h[1] = (_Float16)f[1];
  h[2] = (_Float16)f[2]; h[3] = (_Float16)f[3];
  *(half4_t*)(dst + 4 * j) = h;
}

// ------------------------------------------- K2: qkv GEMM (M=4096,N=2304,K=768)
// cols 0..1535 (q,k) -> qkh[token][1536]; cols 1536.. (v) -> vth[bh][64][2048]
__global__ __launch_bounds__(256) void qkv_gemm(const _Float16* __restrict__ xh,
                                                const _Float16* __restrict__ wh,
                                                const float* __restrict__ bias,
                                                _Float16* __restrict__ qkh,
                                                _Float16* __restrict__ vth) {
  __shared__ __align__(16) _Float16 sA[128 * LDA];
  __shared__ __align__(16) _Float16 sB[128 * LDA];
  const int tid = threadIdx.x;
  const int nblk = blockIdx.x % 18, mblk = blockIdx.x / 18;
  const int lane = tid & 63, w = tid >> 6;
  const int lane15 = lane & 15, quad = lane >> 4;
  const int wm = w >> 1, wn = w & 1;
  const int chunk = tid & 7, rbase = tid >> 3;

  const int Abase = mblk * 128 * 768;
  const int Bbase = nblk * 128 * 768;

  floatx4 acc[4][4];
#pragma unroll
  for (int mt = 0; mt < 4; ++mt)
#pragma unroll
    for (int nt = 0; nt < 4; ++nt) acc[mt][nt] = (floatx4){0.f, 0.f, 0.f, 0.f};

  for (int kt = 0; kt < 12; ++kt) {
    half8 ta[4], tb[4];
#pragma unroll
    for (int i = 0; i < 4; ++i) {
      int row = rbase + 32 * i;
      ta[i] = *(const half8*)(xh + Abase + row * 768 + kt * 64 + chunk * 8);
      tb[i] = *(const half8*)(wh + Bbase + row * 768 + kt * 64 + chunk * 8);
    }
    if (kt) __syncthreads();
#pragma unroll
    for (int i = 0; i < 4; ++i) {
      int row = rbase + 32 * i;
      *(half8*)(sA + row * LDA + chunk * 8) = ta[i];
      *(half8*)(sB + row * LDA + chunk * 8) = tb[i];
    }
    __syncthreads();
#pragma unroll
    for (int ks = 0; ks < 2; ++ks) {
      half8 af[4], bf[4];
#pragma unroll
      for (int mt = 0; mt < 4; ++mt)
        af[mt] = *(const half8*)(sA + (wm * 64 + mt * 16 + lane15) * LDA + ks * 32 + quad * 8);
#pragma unroll
      for (int nt = 0; nt < 4; ++nt)
        bf[nt] = *(const half8*)(sB + (wn * 64 + nt * 16 + lane15) * LDA + ks * 32 + quad * 8);
#pragma unroll
      for (int mt = 0; mt < 4; ++mt)
#pragma unroll
        for (int nt = 0; nt < 4; ++nt)
          acc[mt][nt] = __builtin_amdgcn_mfma_f32_16x16x32_f16(af[mt], bf[nt], acc[mt][nt], 0, 0, 0);
    }
  }

  const int mbase = mblk * 128 + wm * 64;
  const int nbase = nblk * 128 + wn * 64;
#pragma unroll
  for (int nt = 0; nt < 4; ++nt) {
    int cbase = nbase + nt * 16;           // wave-uniform
    float bv = bias[cbase + lane15];
    if (cbase < 1536) {                    // q,k -> row-major [token][1536]
      int col = cbase + lane15;
#pragma unroll
      for (int mt = 0; mt < 4; ++mt)
#pragma unroll
        for (int r = 0; r < 4; ++r) {
          int token = mbase + mt * 16 + quad * 4 + r;
          qkh[token * 1536 + col] = (_Float16)(acc[mt][nt][r] + bv);
        }
    } else {                               // v -> vth[bh][d][n], packed half4
      int dcol = cbase - 1536 + lane15;
      int h = dcol >> 6, d = dcol & 63;
#pragma unroll
      for (int mt = 0; mt < 4; ++mt) {
        int tok0 = mbase + mt * 16 + quad * 4;
        int b = tok0 >> 11, n0 = tok0 & 2047;
        int bh = b * 12 + h;
        half4_t hv;
#pragma unroll
        for (int r = 0; r < 4; ++r) hv[r] = (_Float16)(acc[mt][nt][r] + bv);
        *(half4_t*)(vth + (bh * 64 + d) * 2048 + n0) = hv;
      }
    }
  }
}

// ---------------------------------------------------------------- K3: attention
// S^T formulation: per wave, 16 queries (= lane15), keys over quad*4+r x nt.
// K/V fragments straight from global (L2-resident); P via per-wave LDS slice.
__global__ __launch_bounds__(256) void attn_fused(const _Float16* __restrict__ qkh,
                                                  const _Float16* __restrict__ vth,
                                                  _Float16* __restrict__ aoh) {
  __shared__ __align__(16) _Float16 sP[4 * 16 * LDP];
  const int tid = threadIdx.x;
  const int bx = blockIdx.x;
  const int bh = bx % 24, qt = bx / 24;    // idx%8 == bh%8 -> per-bh XCD affinity
  const int b = bh / 12, h = bh % 12;
  const int lane = tid & 63, w = tid >> 6;
  const int lane15 = lane & 15, quad = lane >> 4;
  _Float16* sPw = sP + w * 16 * LDP;

  const int qkbase = b * 2048 * 1536 + h * 64;
  const int qrow = qt * 64 + w * 16 + lane15;
  half8 qa0 = *(const half8*)(qkh + qkbase + qrow * 1536 + quad * 8);
  half8 qa1 = *(const half8*)(qkh + qkbase + qrow * 1536 + 32 + quad * 8);

  const _Float16* kptr = qkh + qkbase + 768;         // k cols at +768
  const _Float16* vptr = vth + bh * 64 * 2048;       // [d][n]

  floatx4 O[4];
#pragma unroll
  for (int dt = 0; dt < 4; ++dt) O[dt] = (floatx4){0.f, 0.f, 0.f, 0.f};
  float mrow = -3.0e38f, lrow = 0.f;                 // per-lane: query = lane15

  for (int kt = 0; kt < 32; ++kt) {
    // K fragments: A[m=key=nt*16+lane15][k=d]; V^T frags: B[k=key][n=d=lane15]
    half8 kf[4][2], vf[4][2];
#pragma unroll
    for (int nt = 0; nt < 4; ++nt)
#pragma unroll
      for (int kk = 0; kk < 2; ++kk)
        kf[nt][kk] = *(const half8*)(kptr + (kt * 64 + nt * 16 + lane15) * 1536 + kk * 32 + quad * 8);
#pragma unroll
    for (int dt = 0; dt < 4; ++dt)
#pragma unroll
      for (int kk = 0; kk < 2; ++kk)
        vf[dt][kk] = *(const half8*)(vptr + (dt * 16 + lane15) * 2048 + kt * 64 + kk * 32 + quad * 8);

    // S^T[key][query] = K·Q^T : A=kf, B=qa (B-frag == A-frag register layout)
    floatx4 s[4];
#pragma unroll
    for (int nt = 0; nt < 4; ++nt) {
      floatx4 a = (floatx4){0.f, 0.f, 0.f, 0.f};
      a = __builtin_amdgcn_mfma_f32_16x16x32_f16(kf[nt][0], qa0, a, 0, 0, 0);
      a = __builtin_amdgcn_mfma_f32_16x16x32_f16(kf[nt][1], qa1, a, 0, 0, 0);
#pragma unroll
      for (int r = 0; r < 4; ++r) a[r] *= SCALE_LOG2E;
      s[nt] = a;
    }

    // online softmax: all 16 values in this lane belong to query=lane15;
    // keys spread over (nt, r) in-register and partner lanes lane^16, lane^32.
    float tmax = s[0][0];
#pragma unroll
    for (int nt = 0; nt < 4; ++nt)
#pragma unroll
      for (int r = 0; r < 4; ++r) tmax = fmaxf(tmax, s[nt][r]);
    tmax = fmaxf(tmax, __shfl_xor(tmax, 16, 64));
    tmax = fmaxf(tmax, __shfl_xor(tmax, 32, 64));
    float mnew = fmaxf(mrow, tmax);
    float alpha = exp2f(mrow - mnew);
    float rsum = 0.f;
#pragma unroll
    for (int nt = 0; nt < 4; ++nt)
#pragma unroll
      for (int r = 0; r < 4; ++r) {
        float p = exp2f(s[nt][r] - mnew);
        s[nt][r] = p;
        rsum += p;
      }
    rsum += __shfl_xor(rsum, 16, 64);
    rsum += __shfl_xor(rsum, 32, 64);
    lrow = lrow * alpha + rsum;
    mrow = mnew;

    // rescale O rows (rows = queries quad*4+r; alpha lives at lane15=query)
    float ar[4];
#pragma unroll
    for (int r = 0; r < 4; ++r) ar[r] = __shfl(alpha, 4 * quad + r, 64);
#pragma unroll
    for (int dt = 0; dt < 4; ++dt)
#pragma unroll
      for (int r = 0; r < 4; ++r) O[dt][r] *= ar[r];

    // P^T regs -> sPw[query][key]: lane holds P[lane15][nt*16+quad*4+r]
#pragma unroll
    for (int nt = 0; nt < 4; ++nt) {
      half4_t hp;
#pragma unroll
      for (int r = 0; r < 4; ++r) hp[r] = (_Float16)s[nt][r];
      *(half4_t*)(sPw + lane15 * LDP + nt * 16 + quad * 4) = hp;
    }
    asm volatile("s_waitcnt lgkmcnt(0)" ::: "memory");  // wave-local P visibility

    // PV: A=P[m=query][k=key] from sPw, B=V^T from global
#pragma unroll
    for (int kk = 0; kk < 2; ++kk) {
      half8 pa = *(const half8*)(sPw + lane15 * LDP + kk * 32 + quad * 8);
#pragma unroll
      for (int dt = 0; dt < 4; ++dt)
        O[dt] = __builtin_amdgcn_mfma_f32_16x16x32_f16(pa, vf[dt][kk], O[dt], 0, 0, 0);
    }
    asm volatile("s_waitcnt lgkmcnt(0)" ::: "memory");  // reads done before next writes
  }

  float inv = 1.0f / lrow;
  float ir[4];
#pragma unroll
  for (int r = 0; r < 4; ++r) ir[r] = __shfl(inv, 4 * quad + r, 64);
#pragma unroll
  for (int dt = 0; dt < 4; ++dt)
#pragma unroll
    for (int r = 0; r < 4; ++r) {
      int tok = qt * 64 + w * 16 + quad * 4 + r;
      aoh[(b * 2048 + tok) * 768 + h * 64 + dt * 16 + lane15] = (_Float16)(O[dt][r] * ir[r]);
    }
}

// ------------------------------------------- K4: proj GEMM (M=4096,N=768,K=768)
__global__ __launch_bounds__(256) void proj_gemm(const _Float16* __restrict__ ah,
                                                 const _Float16* __restrict__ wh,
                                                 const float* __restrict__ bias,
                                                 float* __restrict__ out) {
  __shared__ __align__(16) _Float16 sA[128 * LDA];
  __shared__ __align__(16) _Float16 sB[128 * LDA];
  const int tid = threadIdx.x;
  const int nblk = blockIdx.x % 6, mblk = blockIdx.x / 6;
  const int lane = tid & 63, w = tid >> 6;
  const int lane15 = lane & 15, quad = lane >> 4;
  const int wm = w >> 1, wn = w & 1;
  const int chunk = tid & 7, rbase = tid >> 3;

  const int Abase = mblk * 128 * 768;
  const int Bbase = nblk * 128 * 768;

  floatx4 acc[4][4];
#pragma unroll
  for (int mt = 0; mt < 4; ++mt)
#pragma unroll
    for (int nt = 0; nt < 4; ++nt) acc[mt][nt] = (floatx4){0.f, 0.f, 0.f, 0.f};

  for (int kt = 0; kt < 12; ++kt) {
    half8 ta[4], tb[4];
#pragma unroll
    for (int i = 0; i < 4; ++i) {
      int row = rbase + 32 * i;
      ta[i] = *(const half8*)(ah + Abase + row * 768 + kt * 64 + chunk * 8);
      tb[i] = *(const half8*)(wh + Bbase + row * 768 + kt * 64 + chunk * 8);
    }
    if (kt) __syncthreads();
#pragma unroll
    for (int i = 0; i < 4; ++i) {
      int row = rbase + 32 * i;
      *(half8*)(sA + row * LDA + chunk * 8) = ta[i];
      *(half8*)(sB + row * LDA + chunk * 8) = tb[i];
    }
    __syncthreads();
#pragma unroll
    for (int ks = 0; ks < 2; ++ks) {
      half8 af[4], bf[4];
#pragma unroll
      for (int mt = 0; mt < 4; ++mt)
        af[mt] = *(const half8*)(sA + (wm * 64 + mt * 16 + lane15) * LDA + ks * 32 + quad * 8);
#pragma unroll
      for (int nt = 0; nt < 4; ++nt)
        bf[nt] = *(const half8*)(sB + (wn * 64 + nt * 16 + lane15) * LDA + ks * 32 + quad * 8);
#pragma unroll
      for (int mt = 0; mt < 4; ++mt)
#pragma unroll
        for (int nt = 0; nt < 4; ++nt)
          acc[mt][nt] = __builtin_amdgcn_mfma_f32_16x16x32_f16(af[mt], bf[nt], acc[mt][nt], 0, 0, 0);
    }
  }

  const int mbase = mblk * 128 + wm * 64;
  const int nbase = nblk * 128 + wn * 64;
#pragma unroll
  for (int nt = 0; nt < 4; ++nt) {
    int col = nbase + nt * 16 + lane15;
    float bv = bias[col];
#pragma unroll
    for (int mt = 0; mt < 4; ++mt)
#pragma unroll
      for (int r = 0; r < 4; ++r) {
        int token = mbase + mt * 16 + quad * 4 + r;
        out[token * 768 + col] = acc[mt][nt][r] + bv;
      }
  }
}

// ---------------------------------------------------------------- launch
extern "C" void kernel_launch(void* const* d_in, const int* in_sizes, int n_in,
                              void* d_out, int out_size, void* d_ws, size_t ws_size,
                              hipStream_t stream) {
  const float* x     = (const float*)d_in[0];
  // d_in[1] = xpos (unused: rope is None)
  const float* wqkv  = (const float*)d_in[2];
  const float* bqkv  = (const float*)d_in[3];
  const float* wproj = (const float*)d_in[4];
  const float* bproj = (const float*)d_in[5];
  float* out = (float*)d_out;

  _Float16* ws = (_Float16*)d_ws;
  _Float16* xh     = ws + XH_OFF;
  _Float16* wqkvh  = ws + WQKV_OFF;
  _Float16* wprojh = ws + WPROJ_OFF;
  _Float16* qkh    = ws + QK_OFF;
  _Float16* vth    = ws + VTH_OFF;
  _Float16* aoh    = xh;   // x dead after qkv_gemm

  constexpr int total_v4 = (4096 * 768 + 2304 * 768 + 768 * 768) / 4;
  cvt_all<<<total_v4 / 256, 256, 0, stream>>>(x, wqkv, wproj, ws);
  qkv_gemm<<<32 * 18, 256, 0, stream>>>(xh, wqkvh, bqkv, qkh, vth);
  attn_fused<<<24 * 32, 256, 0, stream>>>(qkh, vth, aoh);
  proj_gemm<<<32 * 6, 256, 0, stream>>>(aoh, wprojh, bproj, out);
}

// Round 6
// 190.974 us; speedup vs baseline: 1.5437x; 1.5437x over previous
//
#include <hip/hip_runtime.h>
#include <hip/hip_bf16.h>

// ---------------------------------------------------------------------------
// Attention: B=2,N=2048,C=768,H=12,HD=64.  fp32 in/out, f16 MFMA internals.
//   K1: convert x, W_qkv, W_proj fp32 -> f16 in ws
//   K2: qk[token][1536] = x @ Wqkv^T[:1536] + b ; V^T -> vth[bh][64][2048]
//   K3: flash attention, S^T formulation; K and V^T staged in LDS via
//       coalesced copies (NO transpose), per-wave P in LDS, 2 barriers/tile
//   K4: out = ao @ Wproj^T + b  -> float d_out
// ---------------------------------------------------------------------------

typedef _Float16 half8 __attribute__((ext_vector_type(8)));
typedef _Float16 half4_t __attribute__((ext_vector_type(4)));
typedef float floatx4 __attribute__((ext_vector_type(4)));

#define LDA 72                      // LDS row stride in halves (64+8 pad)
#define LDP 72                      // K3 P-matrix LDS row stride
#define SCALE_LOG2E 0.1803368801111204f   // (1/8) * log2(e)

// ws layout in _Float16 elements (total 14942208 halves = 29.9 MB)
constexpr int XH_OFF    = 0;                          // x as f16: 4096*768
constexpr int WQKV_OFF  = XH_OFF + 4096 * 768;        // 3145728
constexpr int WPROJ_OFF = WQKV_OFF + 2304 * 768;      // 4915200
constexpr int QK_OFF    = WPROJ_OFF + 768 * 768;      // 5505024   [token][1536]
constexpr int VTH_OFF   = QK_OFF + 4096 * 1536;       // 11796480  [bh][64][2048]

// ---------------------------------------------------------------- K1: convert
__global__ __launch_bounds__(256) void cvt_all(const float* __restrict__ x,
                                               const float* __restrict__ wqkv,
                                               const float* __restrict__ wproj,
                                               _Float16* __restrict__ ws) {
  constexpr int n1 = 4096 * 768 / 4;
  constexpr int n2 = 2304 * 768 / 4;
  int i = blockIdx.x * 256 + threadIdx.x;
  const float* src; _Float16* dst; int j;
  if (i < n1)           { src = x;     dst = ws + XH_OFF;    j = i; }
  else if (i < n1 + n2) { src = wqkv;  dst = ws + WQKV_OFF;  j = i - n1; }
  else                  { src = wproj; dst = ws + WPROJ_OFF; j = i - n1 - n2; }
  floatx4 f = *(const floatx4*)(src + 4 * j);
  half4_t h;
  h[0] = (_Float16)f[0]; h[1] = (_Float16)f[1];
  h[2] = (_Float16)f[2]; h[3] = (_Float16)f[3];
  *(half4_t*)(dst + 4 * j) = h;
}

// ------------------------------------------- K2: qkv GEMM (M=4096,N=2304,K=768)
// cols 0..1535 (q,k) -> qkh[token][1536]; cols 1536.. (v) -> vth[bh][64][2048]
__global__ __launch_bounds__(256) void qkv_gemm(const _Float16* __restrict__ xh,
                                                const _Float16* __restrict__ wh,
                                                const float* __restrict__ bias,
                                                _Float16* __restrict__ qkh,
                                                _Float16* __restrict__ vth) {
  __shared__ __align__(16) _Float16 sA[128 * LDA];
  __shared__ __align__(16) _Float16 sB[128 * LDA];
  const int tid = threadIdx.x;
  const int nblk = blockIdx.x % 18, mblk = blockIdx.x / 18;
  const int lane = tid & 63, w = tid >> 6;
  const int lane15 = lane & 15, quad = lane >> 4;
  const int wm = w >> 1, wn = w & 1;
  const int chunk = tid & 7, rbase = tid >> 3;

  const int Abase = mblk * 128 * 768;
  const int Bbase = nblk * 128 * 768;

  floatx4 acc[4][4];
#pragma unroll
  for (int mt = 0; mt < 4; ++mt)
#pragma unroll
    for (int nt = 0; nt < 4; ++nt) acc[mt][nt] = (floatx4){0.f, 0.f, 0.f, 0.f};

  for (int kt = 0; kt < 12; ++kt) {
    half8 ta[4], tb[4];
#pragma unroll
    for (int i = 0; i < 4; ++i) {
      int row = rbase + 32 * i;
      ta[i] = *(const half8*)(xh + Abase + row * 768 + kt * 64 + chunk * 8);
      tb[i] = *(const half8*)(wh + Bbase + row * 768 + kt * 64 + chunk * 8);
    }
    if (kt) __syncthreads();
#pragma unroll
    for (int i = 0; i < 4; ++i) {
      int row = rbase + 32 * i;
      *(half8*)(sA + row * LDA + chunk * 8) = ta[i];
      *(half8*)(sB + row * LDA + chunk * 8) = tb[i];
    }
    __syncthreads();
#pragma unroll
    for (int ks = 0; ks < 2; ++ks) {
      half8 af[4], bf[4];
#pragma unroll
      for (int mt = 0; mt < 4; ++mt)
        af[mt] = *(const half8*)(sA + (wm * 64 + mt * 16 + lane15) * LDA + ks * 32 + quad * 8);
#pragma unroll
      for (int nt = 0; nt < 4; ++nt)
        bf[nt] = *(const half8*)(sB + (wn * 64 + nt * 16 + lane15) * LDA + ks * 32 + quad * 8);
#pragma unroll
      for (int mt = 0; mt < 4; ++mt)
#pragma unroll
        for (int nt = 0; nt < 4; ++nt)
          acc[mt][nt] = __builtin_amdgcn_mfma_f32_16x16x32_f16(af[mt], bf[nt], acc[mt][nt], 0, 0, 0);
    }
  }

  const int mbase = mblk * 128 + wm * 64;
  const int nbase = nblk * 128 + wn * 64;
#pragma unroll
  for (int nt = 0; nt < 4; ++nt) {
    int cbase = nbase + nt * 16;           // wave-uniform
    float bv = bias[cbase + lane15];
    if (cbase < 1536) {                    // q,k -> row-major [token][1536]
      int col = cbase + lane15;
#pragma unroll
      for (int mt = 0; mt < 4; ++mt)
#pragma unroll
        for (int r = 0; r < 4; ++r) {
          int token = mbase + mt * 16 + quad * 4 + r;
          qkh[token * 1536 + col] = (_Float16)(acc[mt][nt][r] + bv);
        }
    } else {                               // v -> vth[bh][d][n], packed half4
      int dcol = cbase - 1536 + lane15;
      int h = dcol >> 6, d = dcol & 63;
#pragma unroll
      for (int mt = 0; mt < 4; ++mt) {
        int tok0 = mbase + mt * 16 + quad * 4;
        int b = tok0 >> 11, n0 = tok0 & 2047;
        int bh = b * 12 + h;
        half4_t hv;
#pragma unroll
        for (int r = 0; r < 4; ++r) hv[r] = (_Float16)(acc[mt][nt][r] + bv);
        *(half4_t*)(vth + (bh * 64 + d) * 2048 + n0) = hv;
      }
    }
  }
}

// ---------------------------------------------------------------- K3: attention
// S^T formulation with LDS-staged K and V^T (coalesced copies, no transpose).
// Per wave: 16 queries (= lane15); keys spread over (nt, quad, r).
__global__ __launch_bounds__(256) void attn_fused(const _Float16* __restrict__ qkh,
                                                  const _Float16* __restrict__ vth,
                                                  _Float16* __restrict__ aoh) {
  __shared__ __align__(16) _Float16 sK[64 * LDA];    // [key][d]
  __shared__ __align__(16) _Float16 sVT[64 * LDA];   // [d][key]  (from global V^T)
  __shared__ __align__(16) _Float16 sP[4 * 16 * LDP];
  const int tid = threadIdx.x;
  const int bx = blockIdx.x;
  const int bh = bx % 24, qt = bx / 24;    // bx%8 == bh%8 -> per-bh XCD affinity
  const int b = bh / 12, h = bh % 12;
  const int lane = tid & 63, w = tid >> 6;
  const int lane15 = lane & 15, quad = lane >> 4;
  const int chunk = tid & 7, rbase = tid >> 3;       // 8 chunks x 32 rows
  _Float16* sPw = sP + w * 16 * LDP;

  const int qkbase = b * 2048 * 1536 + h * 64;
  const int qrow = qt * 64 + w * 16 + lane15;
  half8 qa0 = *(const half8*)(qkh + qkbase + qrow * 1536 + quad * 8);
  half8 qa1 = *(const half8*)(qkh + qkbase + qrow * 1536 + 32 + quad * 8);

  const _Float16* kptr = qkh + qkbase + 768;         // k cols at +768
  const _Float16* vptr = vth + bh * 64 * 2048;       // [d][n]

  floatx4 O[4];
#pragma unroll
  for (int dt = 0; dt < 4; ++dt) O[dt] = (floatx4){0.f, 0.f, 0.f, 0.f};
  float mrow = -3.0e38f, lrow = 0.f;                 // per-lane: query = lane15

  for (int kt = 0; kt < 32; ++kt) {
    // prefetch tile to regs (coalesced: 8 lanes cover one 128B row segment)
    half8 tk[2], tv[2];
#pragma unroll
    for (int i = 0; i < 2; ++i) {
      int row = rbase + 32 * i;
      tk[i] = *(const half8*)(kptr + (kt * 64 + row) * 1536 + chunk * 8);
      tv[i] = *(const half8*)(vptr + row * 2048 + kt * 64 + chunk * 8);
    }
    if (kt) __syncthreads();   // prev tile's LDS reads done
#pragma unroll
    for (int i = 0; i < 2; ++i) {
      int row = rbase + 32 * i;
      *(half8*)(sK + row * LDA + chunk * 8) = tk[i];
      *(half8*)(sVT + row * LDA + chunk * 8) = tv[i];
    }
    __syncthreads();           // staging visible

    // S^T[key][query] = K·Q^T : A = K rows (LDS), B = Q regs
    floatx4 s[4];
#pragma unroll
    for (int nt = 0; nt < 4; ++nt) {
      half8 kf0 = *(const half8*)(sK + (nt * 16 + lane15) * LDA + quad * 8);
      half8 kf1 = *(const half8*)(sK + (nt * 16 + lane15) * LDA + 32 + quad * 8);
      floatx4 a = (floatx4){0.f, 0.f, 0.f, 0.f};
      a = __builtin_amdgcn_mfma_f32_16x16x32_f16(kf0, qa0, a, 0, 0, 0);
      a = __builtin_amdgcn_mfma_f32_16x16x32_f16(kf1, qa1, a, 0, 0, 0);
#pragma unroll
      for (int r = 0; r < 4; ++r) a[r] *= SCALE_LOG2E;
      s[nt] = a;
    }

    // online softmax: all 16 values in this lane belong to query = lane15;
    // partners at lane^16, lane^32 hold the other keys of this query.
    float tmax = s[0][0];
#pragma unroll
    for (int nt = 0; nt < 4; ++nt)
#pragma unroll
      for (int r = 0; r < 4; ++r) tmax = fmaxf(tmax, s[nt][r]);
    tmax = fmaxf(tmax, __shfl_xor(tmax, 16, 64));
    tmax = fmaxf(tmax, __shfl_xor(tmax, 32, 64));
    float mnew = fmaxf(mrow, tmax);
    float alpha = exp2f(mrow - mnew);
    float rsum = 0.f;
#pragma unroll
    for (int nt = 0; nt < 4; ++nt)
#pragma unroll
      for (int r = 0; r < 4; ++r) {
        float p = exp2f(s[nt][r] - mnew);
        s[nt][r] = p;
        rsum += p;
      }
    rsum += __shfl_xor(rsum, 16, 64);
    rsum += __shfl_xor(rsum, 32, 64);
    lrow = lrow * alpha + rsum;
    mrow = mnew;

    // rescale O (rows = queries quad*4+r; alpha lives at lane15 = query)
    float ar[4];
#pragma unroll
    for (int r = 0; r < 4; ++r) ar[r] = __shfl(alpha, 4 * quad + r, 64);
#pragma unroll
    for (int dt = 0; dt < 4; ++dt)
#pragma unroll
      for (int r = 0; r < 4; ++r) O[dt][r] *= ar[r];

    // P^T regs -> sPw[query][key]: lane holds P[lane15][nt*16+quad*4+r]
#pragma unroll
    for (int nt = 0; nt < 4; ++nt) {
      half4_t hp;
#pragma unroll
      for (int r = 0; r < 4; ++r) hp[r] = (_Float16)s[nt][r];
      *(half4_t*)(sPw + lane15 * LDP + nt * 16 + quad * 4) = hp;
    }
    asm volatile("s_waitcnt lgkmcnt(0)" ::: "memory");  // wave-local P visibility

    // PV: A = P (per-wave LDS), B = V^T (shared LDS)
#pragma unroll
    for (int kk = 0; kk < 2; ++kk) {
      half8 pa = *(const half8*)(sPw + lane15 * LDP + kk * 32 + quad * 8);
#pragma unroll
      for (int dt = 0; dt < 4; ++dt) {
        half8 vb = *(const half8*)(sVT + (dt * 16 + lane15) * LDA + kk * 32 + quad * 8);
        O[dt] = __builtin_amdgcn_mfma_f32_16x16x32_f16(pa, vb, O[dt], 0, 0, 0);
      }
    }
  }

  float inv = 1.0f / lrow;
  float ir[4];
#pragma unroll
  for (int r = 0; r < 4; ++r) ir[r] = __shfl(inv, 4 * quad + r, 64);
#pragma unroll
  for (int dt = 0; dt < 4; ++dt)
#pragma unroll
    for (int r = 0; r < 4; ++r) {
      int tok = qt * 64 + w * 16 + quad * 4 + r;
      aoh[(b * 2048 + tok) * 768 + h * 64 + dt * 16 + lane15] = (_Float16)(O[dt][r] * ir[r]);
    }
}

// ------------------------------------------- K4: proj GEMM (M=4096,N=768,K=768)
__global__ __launch_bounds__(256) void proj_gemm(const _Float16* __restrict__ ah,
                                                 const _Float16* __restrict__ wh,
                                                 const float* __restrict__ bias,
                                                 float* __restrict__ out) {
  __shared__ __align__(16) _Float16 sA[128 * LDA];
  __shared__ __align__(16) _Float16 sB[128 * LDA];
  const int tid = threadIdx.x;
  const int nblk = blockIdx.x % 6, mblk = blockIdx.x / 6;
  const int lane = tid & 63, w = tid >> 6;
  const int lane15 = lane & 15, quad = lane >> 4;
  const int wm = w >> 1, wn = w & 1;
  const int chunk = tid & 7, rbase = tid >> 3;

  const int Abase = mblk * 128 * 768;
  const int Bbase = nblk * 128 * 768;

  floatx4 acc[4][4];
#pragma unroll
  for (int mt = 0; mt < 4; ++mt)
#pragma unroll
    for (int nt = 0; nt < 4; ++nt) acc[mt][nt] = (floatx4){0.f, 0.f, 0.f, 0.f};

  for (int kt = 0; kt < 12; ++kt) {
    half8 ta[4], tb[4];
#pragma unroll
    for (int i = 0; i < 4; ++i) {
      int row = rbase + 32 * i;
      ta[i] = *(const half8*)(ah + Abase + row * 768 + kt * 64 + chunk * 8);
      tb[i] = *(const half8*)(wh + Bbase + row * 768 + kt * 64 + chunk * 8);
    }
    if (kt) __syncthreads();
#pragma unroll
    for (int i = 0; i < 4; ++i) {
      int row = rbase + 32 * i;
      *(half8*)(sA + row * LDA + chunk * 8) = ta[i];
      *(half8*)(sB + row * LDA + chunk * 8) = tb[i];
    }
    __syncthreads();
#pragma unroll
    for (int ks = 0; ks < 2; ++ks) {
      half8 af[4], bf[4];
#pragma unroll
      for (int mt = 0; mt < 4; ++mt)
        af[mt] = *(const half8*)(sA + (wm * 64 + mt * 16 + lane15) * LDA + ks * 32 + quad * 8);
#pragma unroll
      for (int nt = 0; nt < 4; ++nt)
        bf[nt] = *(const half8*)(sB + (wn * 64 + nt * 16 + lane15) * LDA + ks * 32 + quad * 8);
#pragma unroll
      for (int mt = 0; mt < 4; ++mt)
#pragma unroll
        for (int nt = 0; nt < 4; ++nt)
          acc[mt][nt] = __builtin_amdgcn_mfma_f32_16x16x32_f16(af[mt], bf[nt], acc[mt][nt], 0, 0, 0);
    }
  }

  const int mbase = mblk * 128 + wm * 64;
  const int nbase = nblk * 128 + wn * 64;
#pragma unroll
  for (int nt = 0; nt < 4; ++nt) {
    int col = nbase + nt * 16 + lane15;
    float bv = bias[col];
#pragma unroll
    for (int mt = 0; mt < 4; ++mt)
#pragma unroll
      for (int r = 0; r < 4; ++r) {
        int token = mbase + mt * 16 + quad * 4 + r;
        out[token * 768 + col] = acc[mt][nt][r] + bv;
      }
  }
}

// ---------------------------------------------------------------- launch
extern "C" void kernel_launch(void* const* d_in, const int* in_sizes, int n_in,
                              void* d_out, int out_size, void* d_ws, size_t ws_size,
                              hipStream_t stream) {
  const float* x     = (const float*)d_in[0];
  // d_in[1] = xpos (unused: rope is None)
  const float* wqkv  = (const float*)d_in[2];
  const float* bqkv  = (const float*)d_in[3];
  const float* wproj = (const float*)d_in[4];
  const float* bproj = (const float*)d_in[5];
  float* out = (float*)d_out;

  _Float16* ws = (_Float16*)d_ws;
  _Float16* xh     = ws + XH_OFF;
  _Float16* wqkvh  = ws + WQKV_OFF;
  _Float16* wprojh = ws + WPROJ_OFF;
  _Float16* qkh    = ws + QK_OFF;
  _Float16* vth    = ws + VTH_OFF;
  _Float16* aoh    = xh;   // x dead after qkv_gemm

  constexpr int total_v4 = (4096 * 768 + 2304 * 768 + 768 * 768) / 4;
  cvt_all<<<total_v4 / 256, 256, 0, stream>>>(x, wqkv, wproj, ws);
  qkv_gemm<<<32 * 18, 256, 0, stream>>>(xh, wqkvh, bqkv, qkh, vth);
  attn_fused<<<24 * 32, 256, 0, stream>>>(qkh, vth, aoh);
  proj_gemm<<<32 * 6, 256, 0, stream>>>(aoh, wprojh, bproj, out);
}